// Round 10
// baseline (51.690 us; speedup 1.0000x reference)
//
#include <hip/hip_runtime.h>

// 1D cubic B-spline field evaluation.
//   dx = 2/(num_cp-3); origin = -1-dx
//   tt = t - origin - dx; q = tt/dx; idx = floor(q); u = q - idx
//   out = sum_{k=0..3} w_k(u) * phi[clamp(idx+k, 0, num_cp-1)]
//
// R2: L1 divergent-gather wall (166us). R3: LDS staging -> 52us. R5: block=512
// + ds_read2 fast path + NT stores -> 47.9us (best). R6-R9: MLP, LDS-traffic/2,
// prefetch, store-side sc0/sc1/nt -- ALL FLAT. Plateau cause: t+out = 256MiB
// = L3 exactly; L3 keeps t/2 (FETCH=66MB) while out fully drains (WRITE=134MB).
// R10: flip L3 ownership -- nontemporal LOADS of t (evict-first, stream past
// L3) + plain temporal stores so out allocates and stays dirty-resident in
// MALL across replays (rewritten in place -> WRITE_SIZE should collapse).

#define MAX_CP_LDS 8192
#define BLOCK 512
#define GRID 2048

typedef float f4v __attribute__((ext_vector_type(4)));

__device__ __forceinline__ float bspline_eval_lds(float tval, const float* sPhi,
                                                  float origin, float dx, float inv_dx,
                                                  int num_cp) {
    float tt = (tval - origin) - dx;   // matches reference op order
    float q  = tt * inv_dx;
    float fidx = floorf(q);
    float u  = q - fidx;
    int idx = (int)fidx;
    int hi  = num_cp - 1;

    float v0, v1, v2, v3;
    if (__builtin_expect((unsigned)idx <= (unsigned)(hi - 3), 1)) {
        // In-range (always true for the bench data): consecutive reads,
        // compiler merges into ds_read2_b32 pairs.
        v0 = sPhi[idx];
        v1 = sPhi[idx + 1];
        v2 = sPhi[idx + 2];
        v3 = sPhi[idx + 3];
    } else {
        int i0 = min(max(idx,     0), hi);
        int i1 = min(max(idx + 1, 0), hi);
        int i2 = min(max(idx + 2, 0), hi);
        int i3 = min(max(idx + 3, 0), hi);
        v0 = sPhi[i0]; v1 = sPhi[i1]; v2 = sPhi[i2]; v3 = sPhi[i3];
    }

    float u2 = u * u;
    float u3 = u2 * u;
    float om = 1.0f - u;
    const float sixth = 1.0f / 6.0f;
    float w0 = om * om * om * sixth;
    float w3 = u3 * sixth;
    float w1 = fmaf(0.5f, u3, fmaf(-1.0f, u2, 2.0f / 3.0f)); // (3u^3-6u^2+4)/6
    float w2 = 1.0f - w0 - w1 - w3;                          // partition of unity

    return fmaf(w0, v0, fmaf(w1, v1, fmaf(w2, v2, w3 * v3)));
}

__global__ __launch_bounds__(BLOCK) void bspline1d_lds_kernel(
    const float* __restrict__ t,
    const float* __restrict__ phi,
    float* __restrict__ out,
    int num_cp, int n)
{
    __shared__ float sPhi[MAX_CP_LDS];

    // Stage phi into LDS with float4 loads.
    {
        const float4* __restrict__ p4 = reinterpret_cast<const float4*>(phi);
        float4* s4 = reinterpret_cast<float4*>(sPhi);
        const int nc4 = num_cp >> 2;
        for (int j = threadIdx.x; j < nc4; j += blockDim.x) {
            s4[j] = p4[j];
        }
        for (int j = (nc4 << 2) + threadIdx.x; j < num_cp; j += blockDim.x) {
            sPhi[j] = phi[j];
        }
    }
    __syncthreads();

    const float dx     = 2.0f / (float)(num_cp - 3);
    const float origin = -1.0f - dx;
    const float inv_dx = (float)(num_cp - 3) * 0.5f;  // 1/dx

    const int tid    = blockIdx.x * blockDim.x + threadIdx.x;
    const int stride = gridDim.x * blockDim.x;
    const int n4     = n >> 2;

    const f4v* __restrict__ t4 = reinterpret_cast<const f4v*>(t);
    f4v* __restrict__ o4       = reinterpret_cast<f4v*>(out);

    for (int i = tid; i < n4; i += stride) {
        // Non-temporal load: t streams past L3 (evict-first) so out can own it.
        f4v tv = __builtin_nontemporal_load(&t4[i]);
        f4v r;
        r.x = bspline_eval_lds(tv.x, sPhi, origin, dx, inv_dx, num_cp);
        r.y = bspline_eval_lds(tv.y, sPhi, origin, dx, inv_dx, num_cp);
        r.z = bspline_eval_lds(tv.z, sPhi, origin, dx, inv_dx, num_cp);
        r.w = bspline_eval_lds(tv.w, sPhi, origin, dx, inv_dx, num_cp);
        o4[i] = r;  // TEMPORAL store: allocate in L3, stay dirty-resident
    }

    for (int j = (n4 << 2) + tid; j < n; j += stride) {
        out[j] = bspline_eval_lds(t[j], sPhi, origin, dx, inv_dx, num_cp);
    }
}

// Fallback for num_cp > LDS capacity (not expected here): gather from global.
__global__ __launch_bounds__(BLOCK) void bspline1d_global_kernel(
    const float* __restrict__ t,
    const float* __restrict__ phi,
    float* __restrict__ out,
    int num_cp, int n)
{
    const float dx     = 2.0f / (float)(num_cp - 3);
    const float origin = -1.0f - dx;
    const float inv_dx = (float)(num_cp - 3) * 0.5f;

    const int tid    = blockIdx.x * blockDim.x + threadIdx.x;
    const int stride = gridDim.x * blockDim.x;
    for (int i = tid; i < n; i += stride) {
        out[i] = bspline_eval_lds(t[i], phi, origin, dx, inv_dx, num_cp);
    }
}

extern "C" void kernel_launch(void* const* d_in, const int* in_sizes, int n_in,
                              void* d_out, int out_size, void* d_ws, size_t ws_size,
                              hipStream_t stream) {
    const float* t   = (const float*)d_in[0];
    const float* phi = (const float*)d_in[1];
    float* out       = (float*)d_out;
    const int n      = in_sizes[0];
    const int num_cp = in_sizes[1];

    if (num_cp <= MAX_CP_LDS) {
        bspline1d_lds_kernel<<<GRID, BLOCK, 0, stream>>>(t, phi, out, num_cp, n);
    } else {
        bspline1d_global_kernel<<<GRID, BLOCK, 0, stream>>>(t, phi, out, num_cp, n);
    }
}

// Round 11
// 47.723 us; speedup vs baseline: 1.0831x; 1.0831x over previous
//
#include <hip/hip_runtime.h>

// 1D cubic B-spline field evaluation.
//   dx = 2/(num_cp-3); origin = -1-dx; q=(t-origin-dx)/dx; idx=floor(q); u=q-idx
//   out = sum_k w_k(u) * phi[clamp(idx+k,0,num_cp-1)]
//
// R2: L1 divergent-gather wall (166us). R3: LDS staging -> 52us. R5: block=512
// + ds_read2 + NT stores -> 47.9us (best). R6-R10: MLP, LDS/2, prefetch,
// store-nt, load-nt ALL FLAT -> cache-policy hints dead; mixed-stream + L3
// thrash sets ~41us copy-equivalent floor. R11: VALU trim -- q via single fma
// ((t+1)*inv_dx), Horner form on tap combos (13 ops vs 16), batched
// addr->loads->poly structure for lgkmcnt pipelining.

#define MAX_CP_LDS 8192
#define BLOCK 512
#define GRID 2048

typedef float f4v __attribute__((ext_vector_type(4)));

// Cubic B-spline via Horner: S(u) = ((a3*u + a2)*u + a1)*u + a0,
//   a0=(v0+4v1+v2)/6, a1=(v2-v0)/2, a2=(v0+v2)/2 - v1, a3=(v3-v0)/6+(v1-v2)/2
__device__ __forceinline__ float spline_horner(float v0, float v1, float v2, float v3,
                                               float u) {
    const float sixth = 1.0f / 6.0f;
    float t1 = v0 + v2;
    float a0 = fmaf(2.0f / 3.0f, v1, t1 * sixth);
    float a1 = 0.5f * (v2 - v0);
    float a2 = fmaf(0.5f, t1, -v1);
    float a3 = fmaf(0.5f, v1 - v2, sixth * (v3 - v0));
    return fmaf(fmaf(fmaf(a3, u, a2), u, a1), u, a0);
}

__device__ __forceinline__ f4v eval4(f4v tv, const float* sPhi,
                                     float inv_dx, int num_cp) {
    const int hi = num_cp - 1;

    // Phase 1: all index/fraction math (no loads yet).
    float q0 = fmaf(tv.x, inv_dx, inv_dx);   // (t+1)/dx
    float q1 = fmaf(tv.y, inv_dx, inv_dx);
    float q2 = fmaf(tv.z, inv_dx, inv_dx);
    float q3 = fmaf(tv.w, inv_dx, inv_dx);
    float f0 = floorf(q0), f1 = floorf(q1), f2 = floorf(q2), f3 = floorf(q3);
    float u0 = q0 - f0, u1 = q1 - f1, u2 = q2 - f2, u3 = q3 - f3;
    int i0 = (int)f0, i1 = (int)f1, i2 = (int)f2, i3 = (int)f3;

    unsigned lim = (unsigned)(hi - 3);
    bool fast = ((unsigned)i0 <= lim) & ((unsigned)i1 <= lim) &
                ((unsigned)i2 <= lim) & ((unsigned)i3 <= lim);

    float v[4][4];
    if (__builtin_expect(fast, 1)) {
        // Phase 2: issue all LDS reads back-to-back (compiler -> 8x ds_read2_b32).
        v[0][0] = sPhi[i0];     v[0][1] = sPhi[i0 + 1];
        v[0][2] = sPhi[i0 + 2]; v[0][3] = sPhi[i0 + 3];
        v[1][0] = sPhi[i1];     v[1][1] = sPhi[i1 + 1];
        v[1][2] = sPhi[i1 + 2]; v[1][3] = sPhi[i1 + 3];
        v[2][0] = sPhi[i2];     v[2][1] = sPhi[i2 + 1];
        v[2][2] = sPhi[i2 + 2]; v[2][3] = sPhi[i2 + 3];
        v[3][0] = sPhi[i3];     v[3][1] = sPhi[i3 + 1];
        v[3][2] = sPhi[i3 + 2]; v[3][3] = sPhi[i3 + 3];
    } else {
        int idx[4] = {i0, i1, i2, i3};
        #pragma unroll
        for (int p = 0; p < 4; ++p) {
            #pragma unroll
            for (int k = 0; k < 4; ++k) {
                v[p][k] = sPhi[min(max(idx[p] + k, 0), hi)];
            }
        }
    }

    // Phase 3: polynomials.
    f4v r;
    r.x = spline_horner(v[0][0], v[0][1], v[0][2], v[0][3], u0);
    r.y = spline_horner(v[1][0], v[1][1], v[1][2], v[1][3], u1);
    r.z = spline_horner(v[2][0], v[2][1], v[2][2], v[2][3], u2);
    r.w = spline_horner(v[3][0], v[3][1], v[3][2], v[3][3], u3);
    return r;
}

__global__ __launch_bounds__(BLOCK) void bspline1d_lds_kernel(
    const float* __restrict__ t,
    const float* __restrict__ phi,
    float* __restrict__ out,
    int num_cp, int n)
{
    __shared__ float sPhi[MAX_CP_LDS];

    // Stage phi into LDS with float4 loads.
    {
        const float4* __restrict__ p4 = reinterpret_cast<const float4*>(phi);
        float4* s4 = reinterpret_cast<float4*>(sPhi);
        const int nc4 = num_cp >> 2;
        for (int j = threadIdx.x; j < nc4; j += blockDim.x) {
            s4[j] = p4[j];
        }
        for (int j = (nc4 << 2) + threadIdx.x; j < num_cp; j += blockDim.x) {
            sPhi[j] = phi[j];
        }
    }
    __syncthreads();

    const float inv_dx = (float)(num_cp - 3) * 0.5f;  // 1/dx; (t+1)/dx = fma(t,inv,inv)

    const int tid    = blockIdx.x * blockDim.x + threadIdx.x;
    const int stride = gridDim.x * blockDim.x;
    const int n4     = n >> 2;

    const f4v* __restrict__ t4 = reinterpret_cast<const f4v*>(t);
    f4v* __restrict__ o4       = reinterpret_cast<f4v*>(out);

    for (int i = tid; i < n4; i += stride) {
        f4v tv = t4[i];
        f4v r = eval4(tv, sPhi, inv_dx, num_cp);
        __builtin_nontemporal_store(r, &o4[i]);  // out never re-read
    }

    // Tail (n not divisible by 4): scalar, exact same math.
    const int hi = num_cp - 1;
    for (int j = (n4 << 2) + tid; j < n; j += stride) {
        float q = fmaf(t[j], inv_dx, inv_dx);
        float f = floorf(q);
        float u = q - f;
        int idx = (int)f;
        int k0 = min(max(idx,     0), hi);
        int k1 = min(max(idx + 1, 0), hi);
        int k2 = min(max(idx + 2, 0), hi);
        int k3 = min(max(idx + 3, 0), hi);
        out[j] = spline_horner(sPhi[k0], sPhi[k1], sPhi[k2], sPhi[k3], u);
    }
}

// Fallback for num_cp > LDS capacity (not expected here): gather from global.
__global__ __launch_bounds__(BLOCK) void bspline1d_global_kernel(
    const float* __restrict__ t,
    const float* __restrict__ phi,
    float* __restrict__ out,
    int num_cp, int n)
{
    const float inv_dx = (float)(num_cp - 3) * 0.5f;
    const int hi = num_cp - 1;

    const int tid    = blockIdx.x * blockDim.x + threadIdx.x;
    const int stride = gridDim.x * blockDim.x;
    for (int i = tid; i < n; i += stride) {
        float q = fmaf(t[i], inv_dx, inv_dx);
        float f = floorf(q);
        float u = q - f;
        int idx = (int)f;
        int k0 = min(max(idx,     0), hi);
        int k1 = min(max(idx + 1, 0), hi);
        int k2 = min(max(idx + 2, 0), hi);
        int k3 = min(max(idx + 3, 0), hi);
        out[i] = spline_horner(phi[k0], phi[k1], phi[k2], phi[k3], u);
    }
}

extern "C" void kernel_launch(void* const* d_in, const int* in_sizes, int n_in,
                              void* d_out, int out_size, void* d_ws, size_t ws_size,
                              hipStream_t stream) {
    const float* t   = (const float*)d_in[0];
    const float* phi = (const float*)d_in[1];
    float* out       = (float*)d_out;
    const int n      = in_sizes[0];
    const int num_cp = in_sizes[1];

    if (num_cp <= MAX_CP_LDS) {
        bspline1d_lds_kernel<<<GRID, BLOCK, 0, stream>>>(t, phi, out, num_cp, n);
    } else {
        bspline1d_global_kernel<<<GRID, BLOCK, 0, stream>>>(t, phi, out, num_cp, n);
    }
}